// Round 10
// baseline (347.624 us; speedup 1.0000x reference)
//
#include <hip/hip_runtime.h>
#include <hip/hip_bf16.h>
#include <stdint.h>

#define DIN 4096
#define DOUT 4096
#define BK 64
#define NT (DIN / BK)   // 64 K-tiles

typedef __attribute__((ext_vector_type(8))) short short8;
typedef __attribute__((ext_vector_type(8))) unsigned short ushort8;
typedef __attribute__((ext_vector_type(4))) float f32x4;

__device__ inline unsigned short f2bf(float f) {
    union { float f; unsigned u; } v; v.f = f;
    unsigned r = v.u + 0x7fffu + ((v.u >> 16) & 1u);   // RNE
    return (unsigned short)(r >> 16);
}

// ---- prep 1: x (f32) -> bf16, 8 elems/thread --------------------------------
__global__ void cvt_x_kernel(const float* __restrict__ x, ushort* __restrict__ xb, long n8) {
    long i = (long)blockIdx.x * blockDim.x + threadIdx.x;
    if (i >= n8) return;
    const float4* p = (const float4*)(x + i * 8);
    float4 v0 = p[0], v1 = p[1];
    ushort8 o;
    o[0] = f2bf(v0.x); o[1] = f2bf(v0.y); o[2] = f2bf(v0.z); o[3] = f2bf(v0.w);
    o[4] = f2bf(v1.x); o[5] = f2bf(v1.y); o[6] = f2bf(v1.z); o[7] = f2bf(v1.w);
    *(ushort8*)(xb + i * 8) = o;
}

// ---- prep 2: Wt[e][d] = bf16(base[d][e] + c*mask[d][e])  (64x64 LDS transpose)
__global__ void make_wt_kernel(const float* __restrict__ base, const int* __restrict__ mask,
                               const float* __restrict__ coeff, ushort* __restrict__ wt) {
    __shared__ float tile[64][65];
    const float c = coeff[0];
    const int t = threadIdx.x;                 // 256 threads
    const int bd = blockIdx.x >> 6;            // d-tile
    const int be = blockIdx.x & 63;            // e-tile
    const int d0 = bd * 64, e0 = be * 64;
#pragma unroll
    for (int i = 0; i < 4; ++i) {
        int idx = i * 256 + t;                 // 0..1023 float4-index
        int r = idx >> 4;                      // d-row 0..63
        int c4 = (idx & 15) << 2;              // e-col
        const float4 bv = *(const float4*)(base + (size_t)(d0 + r) * DOUT + e0 + c4);
        const int4  mv = *(const int4*)(mask + (size_t)(d0 + r) * DOUT + e0 + c4);
        tile[r][c4 + 0] = bv.x + c * (float)mv.x;
        tile[r][c4 + 1] = bv.y + c * (float)mv.y;
        tile[r][c4 + 2] = bv.z + c * (float)mv.z;
        tile[r][c4 + 3] = bv.w + c * (float)mv.w;
    }
    __syncthreads();
#pragma unroll
    for (int i = 0; i < 8; ++i) {
        int idx = i * 256 + t;                 // 0..2047 pair index
        int r = idx >> 5;                      // e-row 0..63
        int p = (idx & 31) << 1;               // d-col pair
        ushort2 o;
        o.x = f2bf(tile[p][r]);
        o.y = f2bf(tile[p + 1][r]);
        *(ushort2*)(wt + (size_t)(e0 + r) * DIN + d0 + p) = o;
    }
}

// ---- GEMM: 256x256 tile, BK=64, TWO fat phases per K-tile -------------------
// Round-10 restructure: per K-tile, 2 phases of 32 MFMA/wave (kk0, kk1) with
// 12 ds_read_b128 each, instead of 4 phases of 16. Halves the per-phase
// barrier+lgkm heads (measured ~640 cyc each, r9) against the same MFMA work.
// Sync proof (all barrier-formal):
//   P1: reads kk0(U); stage kk1(U+1)->1-b [4 GLL]; BAR1; 32 MFMA
//   mid: WAITV(8) drains kk1(U) [staged 3 phases ago]; BAR2  -> P2 reads safe
//   P2: reads kk1(U); stage kk0(U+2)->b [4 GLL]; BAR3; 32 MFMA
//   boundary: WAITV(8) drains kk0(U+1) [3 phases old]; BAR4 -> next P1 safe
// Overwrite safety: P1 stage follows BAR4(U-1) > all P2(U-1) MFMA > kk1(U-1)
// reads drained; P2 stage follows BAR2 > all P1 MFMA > kk0(U) reads drained.
// Tails: mid G1?8:0 ; boundary G2?8:(NEXT?4:skip).

#define MFMA(d, va, vb) d = __builtin_amdgcn_mfma_f32_16x16x32_bf16(va, vb, d, 0, 0, 0)

#define MFMA16(AOFF, x0,x1,x2,x3) \
    MFMA(acc[AOFF+0][0],x0,b0); MFMA(acc[AOFF+0][1],x0,b1); MFMA(acc[AOFF+0][2],x0,b2); MFMA(acc[AOFF+0][3],x0,b3); \
    MFMA(acc[AOFF+1][0],x1,b0); MFMA(acc[AOFF+1][1],x1,b1); MFMA(acc[AOFF+1][2],x1,b2); MFMA(acc[AOFF+1][3],x1,b3); \
    MFMA(acc[AOFF+2][0],x2,b0); MFMA(acc[AOFF+2][1],x2,b1); MFMA(acc[AOFF+2][2],x2,b2); MFMA(acc[AOFF+2][3],x2,b3); \
    MFMA(acc[AOFF+3][0],x3,b0); MFMA(acc[AOFF+3][1],x3,b1); MFMA(acc[AOFF+3][2],x3,b2); MFMA(acc[AOFF+3][3],x3,b3);

#define GLL(P, L) \
    __builtin_amdgcn_global_load_lds( \
        (const __attribute__((address_space(1))) void*)(P), \
        (__attribute__((address_space(3))) void*)(L), 16, 0, 0)

#define RDA(BUF,KK,OH,MM) (*(const short8*)&lA[BUF][KK][aoff + (OH)*2048 + (MM)*512])
#define RDB(BUF,KK,NN)    (*(const short8*)&lB[BUF][KK][boff + (NN)*512])

#define STAGE_A(BUF,KK,OFE) { GLL(gA0 + (OFE), &lA[BUF][KK][doff]); \
                              GLL(gA1 + (OFE), &lA[BUF][KK][doff + 4096]); }
#define STAGE_B(BUF,KK,OFE) { GLL(gB0 + (OFE), &lB[BUF][KK][doff]); \
                              GLL(gB1 + (OFE), &lB[BUF][KK][doff + 4096]); }

#define WAITV(N)  asm volatile("s_waitcnt vmcnt(" #N ")" ::: "memory")
#define SBAR      __builtin_amdgcn_s_barrier()

#define KTILE2(BUF, G1, G2, NEXT, OFE1, OFE2) \
  { \
    short8 a0,a1,a2,a3,a4,a5,a6,a7,b0,b1,b2,b3; \
    /* ---- P1: kk0 ---- */ \
    a0=RDA(BUF,0,0,0); a1=RDA(BUF,0,0,1); a2=RDA(BUF,0,0,2); a3=RDA(BUF,0,0,3); \
    b0=RDB(BUF,0,0);  b1=RDB(BUF,0,1);  b2=RDB(BUF,0,2);  b3=RDB(BUF,0,3); \
    a4=RDA(BUF,0,1,0); a5=RDA(BUF,0,1,1); a6=RDA(BUF,0,1,2); a7=RDA(BUF,0,1,3); \
    if (G1) { STAGE_A(1-(BUF), 1, OFE1) STAGE_B(1-(BUF), 1, OFE1) } \
    SBAR; \
    __builtin_amdgcn_s_setprio(1); \
    MFMA16(0, a0,a1,a2,a3) \
    MFMA16(4, a4,a5,a6,a7) \
    __builtin_amdgcn_s_setprio(0); \
    /* ---- mid sync: kk1(U) landed for all waves ---- */ \
    if (G1) { WAITV(8); } else { WAITV(0); } \
    SBAR; \
    /* ---- P2: kk1 ---- */ \
    a0=RDA(BUF,1,0,0); a1=RDA(BUF,1,0,1); a2=RDA(BUF,1,0,2); a3=RDA(BUF,1,0,3); \
    b0=RDB(BUF,1,0);  b1=RDB(BUF,1,1);  b2=RDB(BUF,1,2);  b3=RDB(BUF,1,3); \
    a4=RDA(BUF,1,1,0); a5=RDA(BUF,1,1,1); a6=RDA(BUF,1,1,2); a7=RDA(BUF,1,1,3); \
    if (G2) { STAGE_A(BUF, 0, OFE2) STAGE_B(BUF, 0, OFE2) } \
    SBAR; \
    __builtin_amdgcn_s_setprio(1); \
    MFMA16(0, a0,a1,a2,a3) \
    MFMA16(4, a4,a5,a6,a7) \
    __builtin_amdgcn_s_setprio(0); \
    /* ---- boundary sync: kk0(U+1) landed for all waves ---- */ \
    if (G2)        { WAITV(8); } \
    else if (NEXT) { WAITV(4); } \
    SBAR; \
    __builtin_amdgcn_sched_barrier(0); \
  }

__global__ __launch_bounds__(512, 2) void gemm_kernel(const ushort* __restrict__ A,
                                                      const ushort* __restrict__ Bt,
                                                      float* __restrict__ C) {
    __shared__ __align__(16) ushort lA[2][2][256 * 32];
    __shared__ __align__(16) ushort lB[2][2][256 * 32];

    const int tid = threadIdx.x;
    const int lane = tid & 63;
    const int wave = tid >> 6;

    const int nbn = DOUT / 256;               // 16
    const int nwg = gridDim.x;                // 512 (multiple of 8)
    int bid = blockIdx.x;
    int cpx = nwg >> 3;
    int s = (bid & 7) * cpx + (bid >> 3);     // XCD-contiguous chunks
    const int m0 = (s / nbn) * 256;
    const int n0 = (s % nbn) * 256;

    const int wr = wave >> 2;                 // 0..1  (M half)
    const int wc = wave & 3;                  // 0..3  (N quarter)
    const int fr = lane & 15;
    const int fq = lane >> 4;                 // 0..3

    const int st_r = tid >> 2;                // 0..127

    // per-thread constant offsets (ushort elems); read swizzle elem-xor ((fr>>1)&3)<<3
    const int sx = ((fr >> 1) & 3) << 3;
    const int aoff = (wr * 128 + fr) * 32 + ((fq << 3) ^ sx);
    const int boff = (wc * 64 + fr) * 32 + ((fq << 3) ^ sx);
    const int doff = tid * 8;                 // linear stage dest
    const int sce = ((tid & 3) << 3) ^ (((st_r >> 1) & 3) << 3);   // inv-swz source
    const ushort* gA0 = A  + (size_t)(m0 + st_r) * DIN + sce;
    const ushort* gA1 = gA0 + (size_t)128 * DIN;
    const ushort* gB0 = Bt + (size_t)(n0 + st_r) * DIN + sce;
    const ushort* gB1 = gB0 + (size_t)128 * DIN;

    f32x4 acc[8][4] = {};

    // prologue: kk0(0), kk1(0), kk0(1) staged (12 GLL/wave);
    // WAITV(8) drains kk0(0) -> entry state = [kk1(0)x4, kk0(1)x4] = steady
    STAGE_A(0, 0, 0)   STAGE_B(0, 0, 0)
    STAGE_A(0, 1, 32)  STAGE_B(0, 1, 32)
    STAGE_A(1, 0, 64)  STAGE_B(1, 0, 64)
    WAITV(8);
    SBAR;
    __builtin_amdgcn_sched_barrier(0);

    for (int u = 0; u < NT; u += 2) {
        KTILE2(0, 1, (u + 2 < NT), 1, 96, 128)
        KTILE2(1, (u + 2 < NT), (u + 3 < NT), (u + 2 < NT), 160, 192)
        gA0 += 128; gA1 += 128; gB0 += 128; gB1 += 128;
    }

    // epilogue: C/D frag layout col=fr, row=fq*4+j
#pragma unroll
    for (int a = 0; a < 8; ++a) {
        int grow = m0 + wr * 128 + (a >> 2) * 64 + (a & 3) * 16 + fq * 4;
#pragma unroll
        for (int n = 0; n < 4; ++n) {
            int gcol = n0 + wc * 64 + n * 16 + fr;
#pragma unroll
            for (int j = 0; j < 4; ++j)
                C[(size_t)(grow + j) * DOUT + gcol] = acc[a][n][j];
        }
    }
}

extern "C" void kernel_launch(void* const* d_in, const int* in_sizes, int n_in,
                              void* d_out, int out_size, void* d_ws, size_t ws_size,
                              hipStream_t stream) {
    const float* x = (const float*)d_in[0];
    const float* base = (const float*)d_in[1];
    const float* coeff = (const float*)d_in[2];
    const int* mask = (const int*)d_in[3];
    float* out = (float*)d_out;

    const int M = in_sizes[0] / DIN;           // 8192
    ushort* xb = (ushort*)d_ws;                // M*DIN bf16  (64 MB)
    ushort* wt = xb + (size_t)M * DIN;         // DOUT*DIN bf16 (32 MB)

    long n8 = (long)M * DIN / 8;
    cvt_x_kernel<<<(int)((n8 + 255) / 256), 256, 0, stream>>>(x, xb, n8);
    make_wt_kernel<<<(DIN / 64) * (DOUT / 64), 256, 0, stream>>>(base, mask, coeff, wt);

    const int nwg = (M / 256) * (DOUT / 256);  // 512
    gemm_kernel<<<nwg, 512, 0, stream>>>(xb, wt, out);
}

// Round 11
// 333.721 us; speedup vs baseline: 1.0417x; 1.0417x over previous
//
#include <hip/hip_runtime.h>
#include <hip/hip_bf16.h>
#include <stdint.h>

#define DIN 4096
#define DOUT 4096
#define BK 64
#define NT (DIN / BK)   // 64 K-tiles

typedef __attribute__((ext_vector_type(8))) short short8;
typedef __attribute__((ext_vector_type(8))) unsigned short ushort8;
typedef __attribute__((ext_vector_type(16))) float f32x16;

__device__ inline unsigned short f2bf(float f) {
    union { float f; unsigned u; } v; v.f = f;
    unsigned r = v.u + 0x7fffu + ((v.u >> 16) & 1u);   // RNE
    return (unsigned short)(r >> 16);
}

// ---- prep 1: x (f32) -> bf16, 8 elems/thread --------------------------------
__global__ void cvt_x_kernel(const float* __restrict__ x, ushort* __restrict__ xb, long n8) {
    long i = (long)blockIdx.x * blockDim.x + threadIdx.x;
    if (i >= n8) return;
    const float4* p = (const float4*)(x + i * 8);
    float4 v0 = p[0], v1 = p[1];
    ushort8 o;
    o[0] = f2bf(v0.x); o[1] = f2bf(v0.y); o[2] = f2bf(v0.z); o[3] = f2bf(v0.w);
    o[4] = f2bf(v1.x); o[5] = f2bf(v1.y); o[6] = f2bf(v1.z); o[7] = f2bf(v1.w);
    *(ushort8*)(xb + i * 8) = o;
}

// ---- prep 2: Wt[e][d] = bf16(base[d][e] + c*mask[d][e])  (64x64 LDS transpose)
__global__ void make_wt_kernel(const float* __restrict__ base, const int* __restrict__ mask,
                               const float* __restrict__ coeff, ushort* __restrict__ wt) {
    __shared__ float tile[64][65];
    const float c = coeff[0];
    const int t = threadIdx.x;                 // 256 threads
    const int bd = blockIdx.x >> 6;            // d-tile
    const int be = blockIdx.x & 63;            // e-tile
    const int d0 = bd * 64, e0 = be * 64;
#pragma unroll
    for (int i = 0; i < 4; ++i) {
        int idx = i * 256 + t;                 // 0..1023 float4-index
        int r = idx >> 4;                      // d-row 0..63
        int c4 = (idx & 15) << 2;              // e-col
        const float4 bv = *(const float4*)(base + (size_t)(d0 + r) * DOUT + e0 + c4);
        const int4  mv = *(const int4*)(mask + (size_t)(d0 + r) * DOUT + e0 + c4);
        tile[r][c4 + 0] = bv.x + c * (float)mv.x;
        tile[r][c4 + 1] = bv.y + c * (float)mv.y;
        tile[r][c4 + 2] = bv.z + c * (float)mv.z;
        tile[r][c4 + 3] = bv.w + c * (float)mv.w;
    }
    __syncthreads();
#pragma unroll
    for (int i = 0; i < 8; ++i) {
        int idx = i * 256 + t;                 // 0..2047 pair index
        int r = idx >> 5;                      // e-row 0..63
        int p = (idx & 31) << 1;               // d-col pair
        ushort2 o;
        o.x = f2bf(tile[p][r]);
        o.y = f2bf(tile[p + 1][r]);
        *(ushort2*)(wt + (size_t)(e0 + r) * DIN + d0 + p) = o;
    }
}

// ---- GEMM: 256x256 tile, BK=64, r9 skeleton + 32x32x16 MFMA -----------------
// Round-11: revert r10's fat phases (regressed); rebuild on r9 (270us, best).
// Single change vs r9: MFMA shape 16x16x32 -> 32x32x16 (m119: 2495 vs 2176 TF
// ceiling, +15%; halves MFMA instructions per phase 16->8). Identical GLL
// sequence, barrier placement, WAITV protocol, stage schedule => r9's sync
// proof carries over verbatim. Per wave: 4x2 tiles of 32x32, acc 8x f32x16.
// A/B frag: row = lane&31, k-chunk = (lane>>5)*8. C/D (m74/m101-verified):
// col = lane&31, row = (reg&3) + 8*(reg>>2) + 4*(lane>>5).

#define MFMA32(D, VA, VB) D = __builtin_amdgcn_mfma_f32_32x32x16_bf16(VA, VB, D, 0, 0, 0)

#define GLL(P, L) \
    __builtin_amdgcn_global_load_lds( \
        (const __attribute__((address_space(1))) void*)(P), \
        (__attribute__((address_space(3))) void*)(L), 16, 0, 0)

// elem index = row*32 + col, col = (S*16 ^ sx16) + (fq1*8 ^ sxe8) precomputed:
// KC in {kc0, kc1} selects the k-slice (S=0/1) with its swizzle applied.
#define RDA(BUF,KK,MM,KC) (*(const short8*)&lA[BUF][KK][aoffA + (MM)*1024 + (KC)])
#define RDB(BUF,KK,NN,KC) (*(const short8*)&lB[BUF][KK][boffB + (NN)*1024 + (KC)])

#define STAGE_A(BUF,KK,OFE) { GLL(gA0 + (OFE), &lA[BUF][KK][doff]); \
                              GLL(gA1 + (OFE), &lA[BUF][KK][doff + 4096]); }
#define STAGE_B(BUF,KK,OFE) { GLL(gB0 + (OFE), &lB[BUF][KK][doff]); \
                              GLL(gB1 + (OFE), &lB[BUF][KK][doff + 4096]); }

#define WAITV(N)  asm volatile("s_waitcnt vmcnt(" #N ")" ::: "memory")
#define SBAR      __builtin_amdgcn_s_barrier()

// 8 MFMA = one output-half (2 m-tiles x 2 n-tiles) x K=32 (two k-slices)
#define MFMA_HALF(C0,C1,C2,C3) \
    MFMA32(C0, a0, b0); MFMA32(C1, a0, b2); MFMA32(C2, a1, b0); MFMA32(C3, a1, b2); \
    MFMA32(C0, a2, b1); MFMA32(C1, a2, b3); MFMA32(C2, a3, b1); MFMA32(C3, a3, b3);

// K-tile: 4 thin phases (r9 cadence). Stage schedule:
//  ph1: stage A.kk1(U+1)->other buf   ph2: stage B.kk1(U+1)
//  ph3: stage A.kk0(U+2)->this buf    ph4: stage B.kk0(U+2)
// vmcnt: mid WAITV(6) after ph1 MFMA; boundary G2?6 : NEXT?0.
#define KTILE(BUF, G1, G2, NEXT, OFE1, OFE2) \
  { \
    short8 a0,a1,a2,a3,b0,b1,b2,b3; \
    /* ph1: kk0, m-tiles 0,1 */ \
    a0=RDA(BUF,0,0,kc0); a2=RDA(BUF,0,0,kc1); a1=RDA(BUF,0,1,kc0); a3=RDA(BUF,0,1,kc1); \
    b0=RDB(BUF,0,0,kc0); b1=RDB(BUF,0,0,kc1); b2=RDB(BUF,0,1,kc0); b3=RDB(BUF,0,1,kc1); \
    if (G1) STAGE_A(1-(BUF), 1, OFE1) \
    SBAR; \
    __builtin_amdgcn_s_setprio(1); \
    MFMA_HALF(c0,c1,c2,c3) \
    __builtin_amdgcn_s_setprio(0); \
    WAITV(6); \
    /* ph2: kk0, m-tiles 2,3 */ \
    a0=RDA(BUF,0,2,kc0); a2=RDA(BUF,0,2,kc1); a1=RDA(BUF,0,3,kc0); a3=RDA(BUF,0,3,kc1); \
    if (G1) STAGE_B(1-(BUF), 1, OFE1) \
    SBAR; \
    __builtin_amdgcn_s_setprio(1); \
    MFMA_HALF(c4,c5,c6,c7) \
    __builtin_amdgcn_s_setprio(0); \
    /* ph3: kk1, m-tiles 0,1 */ \
    a0=RDA(BUF,1,0,kc0); a2=RDA(BUF,1,0,kc1); a1=RDA(BUF,1,1,kc0); a3=RDA(BUF,1,1,kc1); \
    b0=RDB(BUF,1,0,kc0); b1=RDB(BUF,1,0,kc1); b2=RDB(BUF,1,1,kc0); b3=RDB(BUF,1,1,kc1); \
    if (G2) STAGE_A(BUF, 0, OFE2) \
    SBAR; \
    __builtin_amdgcn_s_setprio(1); \
    MFMA_HALF(c0,c1,c2,c3) \
    __builtin_amdgcn_s_setprio(0); \
    /* ph4: kk1, m-tiles 2,3 */ \
    a0=RDA(BUF,1,2,kc0); a2=RDA(BUF,1,2,kc1); a1=RDA(BUF,1,3,kc0); a3=RDA(BUF,1,3,kc1); \
    if (G2) STAGE_B(BUF, 0, OFE2) \
    SBAR; \
    __builtin_amdgcn_s_setprio(1); \
    MFMA_HALF(c4,c5,c6,c7) \
    __builtin_amdgcn_s_setprio(0); \
    if (G2)        { WAITV(6); } \
    else if (NEXT) { WAITV(0); } \
    SBAR; \
    __builtin_amdgcn_sched_barrier(0); \
  }

__global__ __launch_bounds__(512, 2) void gemm_kernel(const ushort* __restrict__ A,
                                                      const ushort* __restrict__ Bt,
                                                      float* __restrict__ C) {
    __shared__ __align__(16) ushort lA[2][2][256 * 32];
    __shared__ __align__(16) ushort lB[2][2][256 * 32];

    const int tid = threadIdx.x;
    const int lane = tid & 63;
    const int wave = tid >> 6;

    const int nbn = DOUT / 256;               // 16
    const int nwg = gridDim.x;                // 512 (multiple of 8)
    int bid = blockIdx.x;
    int cpx = nwg >> 3;
    int s = (bid & 7) * cpx + (bid >> 3);     // XCD-contiguous chunks
    const int m0 = (s / nbn) * 256;
    const int n0 = (s % nbn) * 256;

    const int wr = wave >> 2;                 // 0..1  (M half)
    const int wc = wave & 3;                  // 0..3  (N quarter)
    const int fr = lane & 31;                 // 32x32 frag row
    const int fq = lane >> 5;                 // 0..1  k-chunk

    const int st_r = tid >> 2;                // 0..127

    // read swizzle (same byte-XOR as staged): elem col = base ^ ((row>>1)&3)<<3
    const int sxe = ((fr >> 1) & 3) << 3;     // bits 3-4
    const int sxe8 = sxe & 8, sx16 = sxe & 16;
    const int kc0 = sx16;                     // S=0 k-slice col term
    const int kc1 = 16 ^ sx16;                // S=1
    const int aoffA = fr * 32 + ((fq << 3) ^ sxe8);            // + wr*128*32
    const int aoffA2 = (wr * 128 + fr) * 32 + ((fq << 3) ^ sxe8);
    const int boffB = (wc * 64 + fr) * 32 + ((fq << 3) ^ sxe8);
    #define aoffA aoffA2

    const int doff = tid * 8;                 // linear stage dest
    const int sce = ((tid & 3) << 3) ^ (((st_r >> 1) & 3) << 3);   // inv-swz source
    const ushort* gA0 = A  + (size_t)(m0 + st_r) * DIN + sce;
    const ushort* gA1 = gA0 + (size_t)128 * DIN;
    const ushort* gB0 = Bt + (size_t)(n0 + st_r) * DIN + sce;
    const ushort* gB1 = gB0 + (size_t)128 * DIN;

    f32x16 c0 = {}, c1 = {}, c2 = {}, c3 = {}, c4 = {}, c5 = {}, c6 = {}, c7 = {};

    // prologue: kk0(0), kk1(0), kk0(1) staged (12 GLL/wave); WAITV(6) leaves
    // steady entry state (r9-identical GLL/wait sequence)
    STAGE_A(0, 0, 0)   STAGE_B(0, 0, 0)
    STAGE_A(0, 1, 32)  STAGE_B(0, 1, 32)
    STAGE_A(1, 0, 64)  STAGE_B(1, 0, 64)
    WAITV(6);
    SBAR;
    __builtin_amdgcn_sched_barrier(0);

    for (int u = 0; u < NT; u += 2) {
        KTILE(0, 1, (u + 2 < NT), 1, 96, 128)
        KTILE(1, (u + 2 < NT), (u + 3 < NT), (u + 2 < NT), 160, 192)
        gA0 += 128; gA1 += 128; gB0 += 128; gB1 += 128;
    }

    // epilogue: tile t=(m32*2+n32) in {c0..c7}; C/D: col=fr, row=(r&3)+8*(r>>2)+4*fq
    const int gcb = n0 + wc * 64 + fr;
    const int grb = m0 + wr * 128 + fq * 4;
#define WRT(CT, M32, N32) \
    _Pragma("unroll") \
    for (int r = 0; r < 16; ++r) { \
        int grow = grb + (M32) * 32 + (r & 3) + 8 * (r >> 2); \
        C[(size_t)grow * DOUT + gcb + (N32) * 32] = CT[r]; \
    }
    WRT(c0, 0, 0) WRT(c1, 0, 1) WRT(c2, 1, 0) WRT(c3, 1, 1)
    WRT(c4, 2, 0) WRT(c5, 2, 1) WRT(c6, 3, 0) WRT(c7, 3, 1)
#undef WRT
}

extern "C" void kernel_launch(void* const* d_in, const int* in_sizes, int n_in,
                              void* d_out, int out_size, void* d_ws, size_t ws_size,
                              hipStream_t stream) {
    const float* x = (const float*)d_in[0];
    const float* base = (const float*)d_in[1];
    const float* coeff = (const float*)d_in[2];
    const int* mask = (const int*)d_in[3];
    float* out = (float*)d_out;

    const int M = in_sizes[0] / DIN;           // 8192
    ushort* xb = (ushort*)d_ws;                // M*DIN bf16  (64 MB)
    ushort* wt = xb + (size_t)M * DIN;         // DOUT*DIN bf16 (32 MB)

    long n8 = (long)M * DIN / 8;
    cvt_x_kernel<<<(int)((n8 + 255) / 256), 256, 0, stream>>>(x, xb, n8);
    make_wt_kernel<<<(DIN / 64) * (DOUT / 64), 256, 0, stream>>>(base, mask, coeff, wt);

    const int nwg = (M / 256) * (DOUT / 256);  // 512
    gemm_kernel<<<nwg, 512, 0, stream>>>(xb, wt, out);
}